// Round 7
// baseline (1833.162 us; speedup 1.0000x reference)
//
#include <hip/hip_runtime.h>

typedef unsigned int u32;
typedef unsigned short u16;
typedef unsigned long long u64;

using short8 = __attribute__((ext_vector_type(8))) short;
using f32x4  = __attribute__((ext_vector_type(4))) float;

// ---------- bf16 helpers ----------
__device__ __forceinline__ u32 f2bf(float f) {  // RTN-even
    u32 u = __float_as_uint(f);
    return (u + 0x7fffu + ((u >> 16) & 1u)) >> 16;
}
__device__ __forceinline__ u32 pk(float a, float b) {
    return f2bf(a) | (f2bf(b) << 16);
}
__device__ __forceinline__ u32 f2bf_fast(float f) {  // round-half-up, 2 inst
    return (__float_as_uint(f) + 0x8000u) >> 16;
}
__device__ __forceinline__ u32 pk_fast(float a, float b) {
    return f2bf_fast(a) | (f2bf_fast(b) << 16);
}
// NOTE: v_cvt_pk_bf16_f32 inline asm caused the round-15 failure (operand->half
// ordering unverified). Do NOT reintroduce without a standalone semantics probe.
__device__ __forceinline__ float bflo(u32 u) { return __uint_as_float(u << 16); }
__device__ __forceinline__ float bfhi(u32 u) { return __uint_as_float(u & 0xffff0000u); }
__device__ __forceinline__ float bfu(u16 u) { return __uint_as_float(((u32)u) << 16); }

union U8 { u32 u[4]; short8 v; };

// ---------- input projection + LayerNorm + ReLU (wave per node) ----------
// agg is bf16 [2N][64] (type-split rows). Zero both rows for this node with
// coalesced u32 stores (lanes 0-31 -> row node, lanes 32-63 -> row N+node).
__global__ void k_input_proj(const float* __restrict__ x, const float* __restrict__ in_w,
                             const float* __restrict__ in_b, const float* __restrict__ ln_g,
                             const float* __restrict__ ln_b, u16* __restrict__ hbf,
                             u16* __restrict__ aggB, int n_nodes) {
    const int lane = threadIdx.x & 63;
    const int node = blockIdx.x * 4 + (threadIdx.x >> 6);
    if (node >= n_nodes) return;
    {
        u32* r0 = (u32*)(aggB + (size_t)node * 64);
        u32* r1 = (u32*)(aggB + ((size_t)n_nodes + node) * 64);
        if (lane < 32) r0[lane] = 0u;
        else r1[lane - 32] = 0u;
    }
    float acc = in_b[lane];
#pragma unroll
    for (int k = 0; k < 4; ++k) acc = fmaf(x[node * 4 + k], in_w[k * 64 + lane], acc);
    float s = acc;
#pragma unroll
    for (int off = 32; off > 0; off >>= 1) s += __shfl_xor(s, off);
    float mu = s * (1.f / 64.f);
    float d = acc - mu;
    float vs = d * d;
#pragma unroll
    for (int off = 32; off > 0; off >>= 1) vs += __shfl_xor(vs, off);
    float inv = rsqrtf(vs * (1.f / 64.f) + 1e-5f);
    float hv = fmaxf(d * inv * ln_g[lane] + ln_b[lane], 0.f);
    hbf[(size_t)node * 64 + lane] = (u16)f2bf(hv);
}

// ---------- (type,dst)-sort: histogram(+key), scan, dst-fill, partitioned scatter ----------
__global__ void k_hist(const int* __restrict__ dst, const int* __restrict__ ety,
                       int* __restrict__ cnt, int* __restrict__ key, int M, int N) {
    int i = blockIdx.x * 256 + threadIdx.x;
    if (i < M) {
        int k = (ety[i] & 1) * N + dst[i];
        key[i] = k;
        atomicAdd(&cnt[k], 1);
    }
}

__global__ void k_scan1(int* __restrict__ data, int* __restrict__ part, int N) {
    __shared__ int s[1024];
    const int t = threadIdx.x;
    const int i = blockIdx.x * 1024 + t;
    int v = (i < N) ? data[i] : 0;
    s[t] = v;
    __syncthreads();
#pragma unroll
    for (int d = 1; d < 1024; d <<= 1) {
        int x = (t >= d) ? s[t - d] : 0;
        __syncthreads();
        s[t] += x;
        __syncthreads();
    }
    if (i < N) data[i] = s[t] - v;  // exclusive
    if (t == 1023) part[blockIdx.x] = s[1023];
}

__global__ void k_scan2(int* __restrict__ part, int nb) {
    const int l = threadIdx.x & 63;
    int base = 0;
    for (int s = 0; s < nb; s += 64) {
        int i = s + l;
        int orig = (i < nb) ? part[i] : 0;
        int x = orig;
#pragma unroll
        for (int off = 1; off < 64; off <<= 1) {
            int t = __shfl_up(x, off);
            if (l >= off) x += t;
        }
        if (i < nb) part[i] = base + x - orig;  // exclusive
        base += __shfl(x, 63);
    }
}

__global__ void k_scan3(int* __restrict__ data, const int* __restrict__ part, int N,
                        int saveIdx, int* __restrict__ slot) {
    int i = blockIdx.x * 1024 + threadIdx.x;
    if (i < N) {
        int v = data[i] + part[blockIdx.x];
        data[i] = v;
        if (i == saveIdx) slot[0] = v;  // T0 = # of type-0 edges
    }
}

__global__ void k_filldst(const int* __restrict__ off, int* __restrict__ dstP,
                          int NB, int N, int M) {
    int b = blockIdx.x * 256 + threadIdx.x;
    if (b >= NB) return;
    int s = off[b];
    int e = (b + 1 < NB) ? off[b + 1] : M;
    int d = (b >= N) ? b - N : b;
    for (int p = s; p < e; ++p) dstP[p] = d;
}

// Key-aligned wave split: wave w of type t gets edges [wEdg[t*2049+w], wEdg[t*2049+w+1]),
// boundaries rounded DOWN to the start of the key containing the equal-edge target.
// Guarantees: every (type,dst) key is processed by exactly ONE wave -> plain-store commit.
__global__ void k_wsplit(const int* __restrict__ starts, int* __restrict__ wEdg,
                         int N, int M) {
    int i = blockIdx.x * 256 + threadIdx.x;
    if (i >= 2 * 2049) return;
    int t = i / 2049, w = i % 2049;
    int lo = (t == 0) ? 0 : starts[N];   // starts[N] = T0 (start of first type-1 key)
    int hi = (t == 0) ? starts[N] : M;
    if (w == 2048) { wEdg[i] = hi; return; }
    long long target = lo + (long long)(hi - lo) * w / 2048;
    int a = t * N, b = t * N + N;        // search keys of this type
    while (b - a > 1) {
        int m = (a + b) >> 1;
        if ((long long)starts[m] <= target) a = m; else b = m;
    }
    wEdg[i] = starts[a];                 // start of key containing target
}

// XCD-partitioned scatter (round-8 win): group g commits only its dst partition.
__global__ void k_scatter(const int* __restrict__ src, const int* __restrict__ key,
                          int* __restrict__ cursor, int* __restrict__ srcP,
                          int M, int N, int nd8) {
    const int g = blockIdx.x & 7;
    const int nb = gridDim.x >> 3;
    const int bi = blockIdx.x >> 3;
    for (int e = bi * 256 + threadIdx.x; e < M; e += nb * 256) {
        int k = key[e];
        int d = (k >= N) ? k - N : k;
        if (d / nd8 == g) {
            int pos = atomicAdd(&cursor[k], 1);
            srcP[pos] = src[e] & 0x3FFFFFFF;
        }
    }
}

// ---------- edge message MLP: atomic-free commit, latency-bound -> raise occupancy ----------
// Round-17: key-aligned wave ranges + carry + plain bf16-row stores (WRITE 92.8->63.9MB
// confirmed the mechanism; time flat -> commit path exonerated).
// Round-18 (this round): __launch_bounds__(256,3). Evidence: MfmaUtil 17 + VALUBusy 35
// = 52% issue, 48% stall; FETCH 155MB = L2-miss gather traffic at L3 latency; only
// 2 waves/SIMD to hide it. Budget 512/3=170 VGPR > 128 live (no round-2 cliff: that
// failure was budget==usage at (256,4)); LDS 38912*3=117KB < 160KB -> 3 blocks/CU.
// VERIFY in counters: VGPR_Count must stay 128; if it drops -> allocator cliff, revert.
__global__ __launch_bounds__(256, 3) void k_edge_mlp(
    const u16* __restrict__ hbf, const int* __restrict__ srcP, const int* __restrict__ dstP,
    const float* __restrict__ w1, const float* __restrict__ b1,
    const float* __restrict__ w2, const float* __restrict__ b2,
    u16* __restrict__ aggB, int M, const int* __restrict__ wEdg, int N) {
    __shared__ u16 sMsg[4][4864];   // per-wave msg [col][edge] stride 76

    const int tid = threadIdx.x;
    const int l = tid & 63, wv = tid >> 6;
    const int l15 = l & 15, quad = l >> 4;

    const int half = gridDim.x >> 1;               // 512
    const int ty = (blockIdx.x >= half) ? 1 : 0;
    const int sub = ty ? (int)blockIdx.x - half : (int)blockIdx.x;
    const int wl = sub * 4 + wv;                   // type-local wave id [0,2048)
    const int e0 = wEdg[ty * 2049 + wl];
    const int e1 = wEdg[ty * 2049 + wl + 1];
    u16* aggT = aggB + (size_t)ty * N * 64;

    // ---- register B fragments + bias vectors for this block's type ----
    short8 Bf1[4][4], Bf2[2][4];
    f32x4 b1i[4], b2i[4];
#pragma unroll
    for (int ni = 0; ni < 4; ++ni) {
        const int c = ni * 16 + l15;
        const float bb2 = b2[ty * 64 + c];
        b2i[ni] = f32x4{bb2, bb2, bb2, bb2};
#pragma unroll
        for (int r = 0; r < 4; ++r) b1i[ni][r] = b1[ty * 64 + ni * 16 + quad * 4 + r];
#pragma unroll
        for (int s = 0; s < 4; ++s) {
            U8 tmp;
            const float* wp = w1 + (size_t)ty * 8192 + (size_t)(s * 32 + quad * 8) * 64 + c;
#pragma unroll
            for (int jp = 0; jp < 4; ++jp) tmp.u[jp] = pk(wp[(2 * jp) * 64], wp[(2 * jp + 1) * 64]);
            Bf1[s][ni] = tmp.v;
        }
        // Bf2 with pi-permuted rows: element jj -> row 32*s + 16*(jj>>2) + 4*quad + (jj&3)
#pragma unroll
        for (int s = 0; s < 2; ++s) {
            U8 tmp;
#pragma unroll
            for (int w = 0; w < 4; ++w) {
                const int row = s * 32 + (w >> 1) * 16 + quad * 4 + (w & 1) * 2;
                const float* wp = w2 + (size_t)ty * 4096 + (size_t)row * 64 + c;
                tmp.u[w] = pk(wp[0], wp[64]);
            }
            Bf2[s][ni] = tmp.v;
        }
    }

    u16* msg = sMsg[wv];
    const int nT = (e1 - e0 + 63) >> 6;

    int mdc = 0;             // dstP (raw, clamped) for current tile, lane l = edge l
    int msn = 0, mdn = 0;    // meta for next tile (j+1)
    short8 a1[4][4];
    if (nT > 0) {  // prologue: tile-0 meta + gathers, tile-1 meta
        int ec = min(e0 + l, M - 1);
        int ms = srcP[ec];
        mdc = dstP[ec];
#pragma unroll
        for (int mi = 0; mi < 4; ++mi) {
            int rs = __shfl(ms, mi * 16 + l15);
            int rd = __shfl(mdc, mi * 16 + l15);
#pragma unroll
            for (int s = 0; s < 4; ++s) {
                const int row = (s < 2) ? rs : rd;
                a1[mi][s] = *(const short8*)(hbf + (size_t)row * 64 + (s & 1) * 32 + quad * 8);
            }
        }
        int ecn = min(e0 + 64 + l, M - 1);
        msn = srcP[ecn];
        mdn = dstP[ecn];
    }

    float carry = 0.f;   // partial sum of a key spanning consecutive tiles (wave-local)
    for (int j = 0; j < nT; ++j) {
        const int base = e0 + (j << 6);
        // meta prefetch for tile j+2 (clamped; harmless past end)
        const int ecf = min(base + 128 + l, M - 1);
        const int msf = srcP[ecf];
        const int mdf = dstP[ecf];

        // ---- fused layer1 (swapped) -> in-reg pack -> layer2, per mi ----
#pragma unroll
        for (int mi = 0; mi < 4; ++mi) {
            f32x4 acc[4] = {b1i[0], b1i[1], b1i[2], b1i[3]};  // bias in C-operand
#pragma unroll
            for (int s = 0; s < 4; ++s)
#pragma unroll
                for (int ni = 0; ni < 4; ++ni)
                    acc[ni] = __builtin_amdgcn_mfma_f32_16x16x32_bf16(Bf1[s][ni], a1[mi][s], acc[ni], 0, 0, 0);
            // a1[mi] consumed -> issue next tile's gathers for this mi now
            {
                int rs = __shfl(msn, mi * 16 + l15);
                int rd = __shfl(mdn, mi * 16 + l15);
#pragma unroll
                for (int s = 0; s < 4; ++s) {
                    const int row = (s < 2) ? rs : rd;
                    a1[mi][s] = *(const short8*)(hbf + (size_t)row * 64 + (s & 1) * 32 + quad * 8);
                }
            }
            // relu + in-register pack into layer-2 A-fragments (pi layout)
            U8 pa, pb;
#pragma unroll
            for (int ni = 0; ni < 2; ++ni) {
                float h0 = fmaxf(acc[ni][0], 0.f);
                float h1 = fmaxf(acc[ni][1], 0.f);
                float h2 = fmaxf(acc[ni][2], 0.f);
                float h3 = fmaxf(acc[ni][3], 0.f);
                pa.u[ni * 2] = pk_fast(h0, h1);
                pa.u[ni * 2 + 1] = pk_fast(h2, h3);
            }
#pragma unroll
            for (int ni = 0; ni < 2; ++ni) {
                float h0 = fmaxf(acc[2 + ni][0], 0.f);
                float h1 = fmaxf(acc[2 + ni][1], 0.f);
                float h2 = fmaxf(acc[2 + ni][2], 0.f);
                float h3 = fmaxf(acc[2 + ni][3], 0.f);
                pb.u[ni * 2] = pk_fast(h0, h1);
                pb.u[ni * 2 + 1] = pk_fast(h2, h3);
            }
            // layer 2: lane&15 = out col, regs = edges; bias in C
#pragma unroll
            for (int ni = 0; ni < 4; ++ni) {
                f32x4 tt = __builtin_amdgcn_mfma_f32_16x16x32_bf16(pa.v, Bf2[0][ni], b2i[ni], 0, 0, 0);
                f32x4 m2 = __builtin_amdgcn_mfma_f32_16x16x32_bf16(pb.v, Bf2[1][ni], tt, 0, 0, 0);
                const int c = ni * 16 + l15;
                const int e0v = mi * 16 + quad * 4;
                uint2 w;
                w.x = pk_fast(m2[0], m2[1]);
                w.y = pk_fast(m2[2], m2[3]);
                *(uint2*)(msg + c * 76 + e0v) = w;  // 8B-aligned
            }
        }

        // ---- run-reduction: plain bf16-row stores; carry across tiles ----
        {
            const int eg = base + l;
            const int dvz = (eg < e1) ? mdc : -1;
            const int dprev = __shfl_up(dvz, 1);
            const u64 mask = __ballot((l == 0) || (dvz != dprev));
            const int dnext = (base + 64 < e1) ? __shfl(mdn, 0) : -1;
            float a = carry;
            carry = 0.f;
#pragma unroll
            for (int i = 0; i < 64; i += 4) {
                uint2 pr = *(const uint2*)(msg + l * 76 + i);
                float v0 = bflo(pr.x), v1 = bfhi(pr.x), v2 = bflo(pr.y), v3 = bfhi(pr.y);
#define RR_STEP(ii, vv)                                                         \
                a += (vv);                                                      \
                if ((ii) == 63) {                                               \
                    int dd = __builtin_amdgcn_readlane(dvz, 63);                \
                    if (dd >= 0) {                                              \
                        if (dd == dnext) carry = a;                             \
                        else aggT[(size_t)dd * 64 + l] = (u16)f2bf(a);          \
                    }                                                           \
                } else if ((mask >> ((ii) + 1)) & 1ull) {                       \
                    int dd = __builtin_amdgcn_readlane(dvz, (ii));              \
                    if (dd >= 0) aggT[(size_t)dd * 64 + l] = (u16)f2bf(a);      \
                    a = 0.f;                                                    \
                }
                RR_STEP(i, v0)
                RR_STEP(i + 1, v1)
                RR_STEP(i + 2, v2)
                RR_STEP(i + 3, v3)
#undef RR_STEP
            }
        }
        // rotate meta pipeline
        mdc = mdn;
        msn = msf;
        mdn = mdf;
    }
}

// ---------- GRU via MFMA (bf16 type-split agg, bf16 state), fused readout ----------
__global__ __launch_bounds__(256, 2) void k_gru_gemm(
    u16* __restrict__ aggB, u16* __restrict__ hbf,
    const float* __restrict__ wi, const float* __restrict__ wh,
    const float* __restrict__ bi, const float* __restrict__ bh, int n_nodes, int last,
    const float* __restrict__ ro_w1, const float* __restrict__ ro_b1,
    const float* __restrict__ ro_w2, const float* __restrict__ ro_b2,
    const float* __restrict__ x, const int* __restrict__ node_type, float* __restrict__ out) {
    extern __shared__ u16 smem[];
    u16* sRZ = smem;                 // 128 cols x stride 136 (r|z), K=128=[agg|h]
    u16* sIN = smem + 128 * 136;     // 64 cols x stride 72, K=64 (agg)
    u16* sHN = sIN + 64 * 72;        // 64 cols x stride 72, K=64 (h)
    u16* sTR = sHN + 64 * 72;        // 4 waves x (16 nodes x stride 72) output transpose
    u16* sRO = sTR + 4 * 16 * 72;    // readout W1, 64 cols x stride 72

    const int tid = threadIdx.x;
    const int l = tid & 63, wv = tid >> 6;
    const int l15 = l & 15, quad = l >> 4;
    const f32x4 vz = {0.f, 0.f, 0.f, 0.f};

    for (int u = tid; u < 128 * 64; u += 256) {
        int c = u & 127, k0 = (u >> 7) * 2;
        float v0 = (k0 < 64) ? wi[k0 * 192 + c] : wh[(k0 - 64) * 192 + c];
        float v1 = (k0 < 64) ? wi[(k0 + 1) * 192 + c] : wh[(k0 + 1 - 64) * 192 + c];
        *(u32*)(sRZ + c * 136 + k0) = pk(v0, v1);
    }
    for (int u = tid; u < 64 * 32; u += 256) {
        int c = u & 63, k0 = (u >> 6) * 2;
        *(u32*)(sIN + c * 72 + k0) = pk(wi[k0 * 192 + 128 + c], wi[(k0 + 1) * 192 + 128 + c]);
        *(u32*)(sHN + c * 72 + k0) = pk(wh[k0 * 192 + 128 + c], wh[(k0 + 1) * 192 + 128 + c]);
        *(u32*)(sRO + c * 72 + k0) = pk(ro_w1[k0 * 64 + c], ro_w1[(k0 + 1) * 64 + c]);
    }
    float bR[4], bZ[4], bI[4], bH[4], b1v[4], w2v[4];
#pragma unroll
    for (int nt = 0; nt < 4; ++nt) {
        int j = nt * 16 + l15;
        bR[nt] = bi[j] + bh[j];
        bZ[nt] = bi[64 + j] + bh[64 + j];
        bI[nt] = bi[128 + j];
        bH[nt] = bh[128 + j];
        b1v[nt] = ro_b1[j];
        w2v[nt] = ro_w2[j];
    }
    const float b2s = ro_b2[0];
    __syncthreads();  // the only barrier

    u16* tr = sTR + wv * (16 * 72);
    const int n_tiles = (n_nodes + 15) >> 4;
    const int g = blockIdx.x & 7, jb = blockIdx.x >> 3, nbg = gridDim.x >> 3;
    const int per8 = (n_tiles + 7) >> 3;
    const int glo = g * per8, ghi = min(glo + per8, n_tiles);
    for (int tile = glo + jb * 4 + wv; tile < ghi; tile += nbg * 4) {
        const int nb = tile << 4;
        const int arow = nb + l15;
        const int rowc = (arow < n_nodes) ? arow : (n_nodes - 1);
        short8 aA0[2], aA1[2], aH[2];
#pragma unroll
        for (int s = 0; s < 2; ++s) {
            aA0[s] = *(const short8*)(aggB + (size_t)rowc * 64 + s * 32 + quad * 8);
            aA1[s] = *(const short8*)(aggB + ((size_t)n_nodes + rowc) * 64 + s * 32 + quad * 8);
            aH[s]  = *(const short8*)(hbf + (size_t)rowc * 64 + s * 32 + quad * 8);
        }
        // re-zero both agg rows for the next layer (rows exclusively ours; skip on last)
        if (!last && arow < n_nodes) {
            const uint4 z16 = {0u, 0u, 0u, 0u};
#pragma unroll
            for (int s = 0; s < 2; ++s) {
                *(uint4*)(aggB + (size_t)rowc * 64 + s * 32 + quad * 8) = z16;
                *(uint4*)(aggB + ((size_t)n_nodes + rowc) * 64 + s * 32 + quad * 8) = z16;
            }
        }
        f32x4 D[16];
#pragma unroll
        for (int i = 0; i < 16; ++i) D[i] = vz;
#pragma unroll
        for (int nt = 0; nt < 8; ++nt) {
            const u16* bp = sRZ + (nt * 16 + l15) * 136 + quad * 8;
            D[nt] = __builtin_amdgcn_mfma_f32_16x16x32_bf16(aA0[0], *(const short8*)bp, D[nt], 0, 0, 0);
            D[nt] = __builtin_amdgcn_mfma_f32_16x16x32_bf16(aA0[1], *(const short8*)(bp + 32), D[nt], 0, 0, 0);
            D[nt] = __builtin_amdgcn_mfma_f32_16x16x32_bf16(aA1[0], *(const short8*)bp, D[nt], 0, 0, 0);
            D[nt] = __builtin_amdgcn_mfma_f32_16x16x32_bf16(aA1[1], *(const short8*)(bp + 32), D[nt], 0, 0, 0);
            D[nt] = __builtin_amdgcn_mfma_f32_16x16x32_bf16(aH[0], *(const short8*)(bp + 64), D[nt], 0, 0, 0);
            D[nt] = __builtin_amdgcn_mfma_f32_16x16x32_bf16(aH[1], *(const short8*)(bp + 96), D[nt], 0, 0, 0);
        }
#pragma unroll
        for (int nt = 0; nt < 4; ++nt) {
            const u16* ip = sIN + (nt * 16 + l15) * 72 + quad * 8;
            D[8 + nt] = __builtin_amdgcn_mfma_f32_16x16x32_bf16(aA0[0], *(const short8*)ip, D[8 + nt], 0, 0, 0);
            D[8 + nt] = __builtin_amdgcn_mfma_f32_16x16x32_bf16(aA0[1], *(const short8*)(ip + 32), D[8 + nt], 0, 0, 0);
            D[8 + nt] = __builtin_amdgcn_mfma_f32_16x16x32_bf16(aA1[0], *(const short8*)ip, D[8 + nt], 0, 0, 0);
            D[8 + nt] = __builtin_amdgcn_mfma_f32_16x16x32_bf16(aA1[1], *(const short8*)(ip + 32), D[8 + nt], 0, 0, 0);
            const u16* hp = sHN + (nt * 16 + l15) * 72 + quad * 8;
            D[12 + nt] = __builtin_amdgcn_mfma_f32_16x16x32_bf16(aH[0], *(const short8*)hp, D[12 + nt], 0, 0, 0);
            D[12 + nt] = __builtin_amdgcn_mfma_f32_16x16x32_bf16(aH[1], *(const short8*)(hp + 32), D[12 + nt], 0, 0, 0);
        }
#pragma unroll
        for (int nt = 0; nt < 4; ++nt) {
            const int j = nt * 16 + l15;
#pragma unroll
            for (int r = 0; r < 4; ++r) {
                const int nd = nb + quad * 4 + r;
                float rsv = D[nt][r] + bR[nt];
                float zsv = D[4 + nt][r] + bZ[nt];
                float inv = D[8 + nt][r] + bI[nt];
                float hnv = D[12 + nt][r] + bH[nt];
                float rr = 1.f / (1.f + __expf(-rsv));
                float zz = 1.f / (1.f + __expf(-zsv));
                float nn = tanhf(fmaf(rr, hnv, inv));
                float hv = (nd < n_nodes) ? bfu(hbf[(size_t)nd * 64 + j]) : 0.f;
                float nh = (1.f - zz) * nn + zz * hv;
                tr[(quad * 4 + r) * 72 + j] = (u16)f2bf(nh);
            }
        }
        {   // coalesced write-back: lane covers 32 contiguous bytes of one node
            const int nd = nb + (l >> 2);
            if (nd < n_nodes) {
                const u16* sp = tr + (l >> 2) * 72 + (l & 3) * 16;
                uint4 va = *(const uint4*)sp;
                uint4 vb = *(const uint4*)(sp + 8);
                u16* dp = hbf + (size_t)nd * 64 + (l & 3) * 16;
                *(uint4*)dp = va;
                *(uint4*)(dp + 8) = vb;
            }
        }
        if (last) {  // fused readout
            short8 ar0 = *(const short8*)(tr + l15 * 72 + quad * 8);
            short8 ar1 = *(const short8*)(tr + l15 * 72 + 32 + quad * 8);
            float p[4] = {0.f, 0.f, 0.f, 0.f};
#pragma unroll
            for (int nt = 0; nt < 4; ++nt) {
                const u16* bp = sRO + (nt * 16 + l15) * 72 + quad * 8;
                f32x4 acc = __builtin_amdgcn_mfma_f32_16x16x32_bf16(ar0, *(const short8*)bp, vz, 0, 0, 0);
                acc = __builtin_amdgcn_mfma_f32_16x16x32_bf16(ar1, *(const short8*)(bp + 32), acc, 0, 0, 0);
#pragma unroll
                for (int r = 0; r < 4; ++r)
                    p[r] += fmaxf(acc[r] + b1v[nt], 0.f) * w2v[nt];
            }
#pragma unroll
            for (int off = 1; off < 16; off <<= 1)
#pragma unroll
                for (int r = 0; r < 4; ++r) p[r] += __shfl_xor(p[r], off);
            if (l15 == 0) {
#pragma unroll
                for (int r = 0; r < 4; ++r) {
                    const int nd = nb + quad * 4 + r;
                    if (nd < n_nodes) {
                        float o = p[r] + b2s;
                        out[nd] = (node_type[nd] == 0) ? (x[nd * 4] + o) : 0.f;
                    }
                }
            }
        }
    }
}

extern "C" void kernel_launch(void* const* d_in, const int* in_sizes, int n_in, void* d_out,
                              int out_size, void* d_ws, size_t ws_size, hipStream_t stream) {
    const float* x = (const float*)d_in[0];
    const int* node_type = (const int*)d_in[1];
    const int* edge_index = (const int*)d_in[2];
    const int* edge_type = (const int*)d_in[3];
    const float* in_w = (const float*)d_in[4];
    const float* in_b = (const float*)d_in[5];
    const float* ln_g = (const float*)d_in[6];
    const float* ln_b = (const float*)d_in[7];
    const float* mlp_w1 = (const float*)d_in[8];
    const float* mlp_b1 = (const float*)d_in[9];
    const float* mlp_w2 = (const float*)d_in[10];
    const float* mlp_b2 = (const float*)d_in[11];
    const float* gru_wi = (const float*)d_in[12];
    const float* gru_wh = (const float*)d_in[13];
    const float* gru_bi = (const float*)d_in[14];
    const float* gru_bh = (const float*)d_in[15];
    const float* ro_w1 = (const float*)d_in[16];
    const float* ro_b1 = (const float*)d_in[17];
    const float* ro_w2 = (const float*)d_in[18];
    const float* ro_b2 = (const float*)d_in[19];

    const int N = in_sizes[1];  // nodes
    const int M = in_sizes[3];  // edges
    const int* src = edge_index;
    const int* dst = edge_index + M;

    // ws: aggB bf16 [2N][64] | hbf (N*128B) | off (2N*4) | part (4KB) | srcP | dstP | key | wEdg
    char* wsb = (char*)d_ws;
    u16* aggB = (u16*)wsb;
    u16* hbf = (u16*)(wsb + (size_t)N * 256);
    int* off = (int*)(wsb + (size_t)N * 384);
    int* part = (int*)(wsb + (size_t)N * 384 + (size_t)2 * N * 4);
    int* srcP = (int*)(wsb + (size_t)N * 384 + (size_t)2 * N * 4 + 4096);
    int* dstP = srcP + M;
    int* key = dstP + M;
    int* wEdg = key + M;
    int* t0slot = part + 1000;

    const int NB = 2 * N;
    const int nb = (NB + 1023) / 1024;
    const int nd8 = (N + 7) / 8;

    // build (type,dst)-sorted edge permutation (reused by all 3 layers)
    hipMemsetAsync(off, 0, (size_t)NB * sizeof(int), stream);
    k_hist<<<(M + 255) / 256, 256, 0, stream>>>(dst, edge_type, off, key, M, N);
    k_scan1<<<nb, 1024, 0, stream>>>(off, part, NB);
    k_scan2<<<1, 64, 0, stream>>>(part, nb);
    k_scan3<<<nb, 1024, 0, stream>>>(off, part, NB, N, t0slot);
    k_filldst<<<(NB + 255) / 256, 256, 0, stream>>>(off, dstP, NB, N, M);
    k_wsplit<<<(2 * 2049 + 255) / 256, 256, 0, stream>>>(off, wEdg, N, M);  // off = starts here
    k_scatter<<<2048, 256, 0, stream>>>(src, key, off, srcP, M, N, nd8);    // mutates off

    k_input_proj<<<(N + 3) / 4, 256, 0, stream>>>(x, in_w, in_b, ln_g, ln_b, hbf, aggB, N);
    const size_t gruLds =
        (size_t)(128 * 136 + 64 * 72 + 64 * 72 + 4 * 16 * 72 + 64 * 72) * sizeof(u16);  // 71680
    for (int l = 0; l < 3; ++l) {
        k_edge_mlp<<<1024, 256, 0, stream>>>(hbf, srcP, dstP,
                                             mlp_w1 + (size_t)l * 2 * 128 * 64,
                                             mlp_b1 + (size_t)l * 2 * 64,
                                             mlp_w2 + (size_t)l * 2 * 64 * 64,
                                             mlp_b2 + (size_t)l * 2 * 64,
                                             aggB, M, wEdg, N);
        k_gru_gemm<<<1024, 256, gruLds, stream>>>(aggB, hbf, gru_wi + (size_t)l * 64 * 192,
                                                  gru_wh + (size_t)l * 64 * 192,
                                                  gru_bi + (size_t)l * 192, gru_bh + (size_t)l * 192,
                                                  N, (l == 2) ? 1 : 0,
                                                  ro_w1, ro_b1, ro_w2, ro_b2,
                                                  x, node_type, (float*)d_out);
    }
}

// Round 8
// 756.481 us; speedup vs baseline: 2.4233x; 2.4233x over previous
//
#include <hip/hip_runtime.h>

typedef unsigned int u32;
typedef unsigned short u16;
typedef unsigned long long u64;

using short8 = __attribute__((ext_vector_type(8))) short;
using f32x4  = __attribute__((ext_vector_type(4))) float;

// ---------- bf16 helpers ----------
__device__ __forceinline__ u32 f2bf(float f) {  // RTN-even
    u32 u = __float_as_uint(f);
    return (u + 0x7fffu + ((u >> 16) & 1u)) >> 16;
}
__device__ __forceinline__ u32 pk(float a, float b) {
    return f2bf(a) | (f2bf(b) << 16);
}
__device__ __forceinline__ u32 f2bf_fast(float f) {  // round-half-up, 2 inst
    return (__float_as_uint(f) + 0x8000u) >> 16;
}
__device__ __forceinline__ u32 pk_fast(float a, float b) {
    return f2bf_fast(a) | (f2bf_fast(b) << 16);
}
// NOTE: v_cvt_pk_bf16_f32 inline asm caused the round-15 failure (operand->half
// ordering unverified). Do NOT reintroduce without a standalone semantics probe.
__device__ __forceinline__ float bflo(u32 u) { return __uint_as_float(u << 16); }
__device__ __forceinline__ float bfhi(u32 u) { return __uint_as_float(u & 0xffff0000u); }
__device__ __forceinline__ float bfu(u16 u) { return __uint_as_float(((u32)u) << 16); }

union U8 { u32 u[4]; short8 v; };

// ---------- input projection + LayerNorm + ReLU (wave per node) ----------
// agg is bf16 [2N][64] (type-split rows). Zero both rows for this node with
// coalesced u32 stores (lanes 0-31 -> row node, lanes 32-63 -> row N+node).
__global__ void k_input_proj(const float* __restrict__ x, const float* __restrict__ in_w,
                             const float* __restrict__ in_b, const float* __restrict__ ln_g,
                             const float* __restrict__ ln_b, u16* __restrict__ hbf,
                             u16* __restrict__ aggB, int n_nodes) {
    const int lane = threadIdx.x & 63;
    const int node = blockIdx.x * 4 + (threadIdx.x >> 6);
    if (node >= n_nodes) return;
    {
        u32* r0 = (u32*)(aggB + (size_t)node * 64);
        u32* r1 = (u32*)(aggB + ((size_t)n_nodes + node) * 64);
        if (lane < 32) r0[lane] = 0u;
        else r1[lane - 32] = 0u;
    }
    float acc = in_b[lane];
#pragma unroll
    for (int k = 0; k < 4; ++k) acc = fmaf(x[node * 4 + k], in_w[k * 64 + lane], acc);
    float s = acc;
#pragma unroll
    for (int off = 32; off > 0; off >>= 1) s += __shfl_xor(s, off);
    float mu = s * (1.f / 64.f);
    float d = acc - mu;
    float vs = d * d;
#pragma unroll
    for (int off = 32; off > 0; off >>= 1) vs += __shfl_xor(vs, off);
    float inv = rsqrtf(vs * (1.f / 64.f) + 1e-5f);
    float hv = fmaxf(d * inv * ln_g[lane] + ln_b[lane], 0.f);
    hbf[(size_t)node * 64 + lane] = (u16)f2bf(hv);
}

// ---------- (type,dst)-sort: histogram(+key), scan, dst-fill, partitioned scatter ----------
__global__ void k_hist(const int* __restrict__ dst, const int* __restrict__ ety,
                       int* __restrict__ cnt, int* __restrict__ key, int M, int N) {
    int i = blockIdx.x * 256 + threadIdx.x;
    if (i < M) {
        int k = (ety[i] & 1) * N + dst[i];
        key[i] = k;
        atomicAdd(&cnt[k], 1);
    }
}

__global__ void k_scan1(int* __restrict__ data, int* __restrict__ part, int N) {
    __shared__ int s[1024];
    const int t = threadIdx.x;
    const int i = blockIdx.x * 1024 + t;
    int v = (i < N) ? data[i] : 0;
    s[t] = v;
    __syncthreads();
#pragma unroll
    for (int d = 1; d < 1024; d <<= 1) {
        int x = (t >= d) ? s[t - d] : 0;
        __syncthreads();
        s[t] += x;
        __syncthreads();
    }
    if (i < N) data[i] = s[t] - v;  // exclusive
    if (t == 1023) part[blockIdx.x] = s[1023];
}

__global__ void k_scan2(int* __restrict__ part, int nb) {
    const int l = threadIdx.x & 63;
    int base = 0;
    for (int s = 0; s < nb; s += 64) {
        int i = s + l;
        int orig = (i < nb) ? part[i] : 0;
        int x = orig;
#pragma unroll
        for (int off = 1; off < 64; off <<= 1) {
            int t = __shfl_up(x, off);
            if (l >= off) x += t;
        }
        if (i < nb) part[i] = base + x - orig;  // exclusive
        base += __shfl(x, 63);
    }
}

__global__ void k_scan3(int* __restrict__ data, const int* __restrict__ part, int N,
                        int saveIdx, int* __restrict__ slot) {
    int i = blockIdx.x * 1024 + threadIdx.x;
    if (i < N) {
        int v = data[i] + part[blockIdx.x];
        data[i] = v;
        if (i == saveIdx) slot[0] = v;  // T0 = # of type-0 edges
    }
}

__global__ void k_filldst(const int* __restrict__ off, int* __restrict__ dstP,
                          int NB, int N, int M) {
    int b = blockIdx.x * 256 + threadIdx.x;
    if (b >= NB) return;
    int s = off[b];
    int e = (b + 1 < NB) ? off[b + 1] : M;
    int d = (b >= N) ? b - N : b;
    for (int p = s; p < e; ++p) dstP[p] = d;
}

// Key-aligned wave split: wave w of type t gets edges [wEdg[t*2049+w], wEdg[t*2049+w+1]),
// boundaries rounded DOWN to the start of the key containing the equal-edge target.
// Guarantees: every (type,dst) key is processed by exactly ONE wave -> plain-store commit.
__global__ void k_wsplit(const int* __restrict__ starts, int* __restrict__ wEdg,
                         int N, int M) {
    int i = blockIdx.x * 256 + threadIdx.x;
    if (i >= 2 * 2049) return;
    int t = i / 2049, w = i % 2049;
    int lo = (t == 0) ? 0 : starts[N];   // starts[N] = T0 (start of first type-1 key)
    int hi = (t == 0) ? starts[N] : M;
    if (w == 2048) { wEdg[i] = hi; return; }
    long long target = lo + (long long)(hi - lo) * w / 2048;
    int a = t * N, b = t * N + N;        // search keys of this type
    while (b - a > 1) {
        int m = (a + b) >> 1;
        if ((long long)starts[m] <= target) a = m; else b = m;
    }
    wEdg[i] = starts[a];                 // start of key containing target
}

// XCD-partitioned scatter (round-8 win): group g commits only its dst partition.
__global__ void k_scatter(const int* __restrict__ src, const int* __restrict__ key,
                          int* __restrict__ cursor, int* __restrict__ srcP,
                          int M, int N, int nd8) {
    const int g = blockIdx.x & 7;
    const int nb = gridDim.x >> 3;
    const int bi = blockIdx.x >> 3;
    for (int e = bi * 256 + threadIdx.x; e < M; e += nb * 256) {
        int k = key[e];
        int d = (k >= N) ? k - N : k;
        if (d / nd8 == g) {
            int pos = atomicAdd(&cursor[k], 1);
            srcP[pos] = src[e] & 0x3FFFFFFF;
        }
    }
}

// ---------- edge message MLP: atomic-free commit ----------
// Round-17: key-aligned wave ranges + carry + plain bf16-row stores.
// Round-18/19 lesson (JOURNALED, twice-confirmed): codegen is only sane at (256,2).
// (256,4) -> VGPR 64 + spills (447us); (256,3) -> VGPR 84 + spills (517us). The
// allocator collapses under any tighter budget. NEVER raise launch_bounds here.
__global__ __launch_bounds__(256, 2) void k_edge_mlp(
    const u16* __restrict__ hbf, const int* __restrict__ srcP, const int* __restrict__ dstP,
    const float* __restrict__ w1, const float* __restrict__ b1,
    const float* __restrict__ w2, const float* __restrict__ b2,
    u16* __restrict__ aggB, int M, const int* __restrict__ wEdg, int N) {
    __shared__ u16 sMsg[4][4864];   // per-wave msg [col][edge] stride 76

    const int tid = threadIdx.x;
    const int l = tid & 63, wv = tid >> 6;
    const int l15 = l & 15, quad = l >> 4;

    const int half = gridDim.x >> 1;               // 512
    const int ty = (blockIdx.x >= half) ? 1 : 0;
    const int sub = ty ? (int)blockIdx.x - half : (int)blockIdx.x;
    const int wl = sub * 4 + wv;                   // type-local wave id [0,2048)
    const int e0 = wEdg[ty * 2049 + wl];
    const int e1 = wEdg[ty * 2049 + wl + 1];
    u16* aggT = aggB + (size_t)ty * N * 64;

    // ---- register B fragments + bias vectors for this block's type ----
    short8 Bf1[4][4], Bf2[2][4];
    f32x4 b1i[4], b2i[4];
#pragma unroll
    for (int ni = 0; ni < 4; ++ni) {
        const int c = ni * 16 + l15;
        const float bb2 = b2[ty * 64 + c];
        b2i[ni] = f32x4{bb2, bb2, bb2, bb2};
#pragma unroll
        for (int r = 0; r < 4; ++r) b1i[ni][r] = b1[ty * 64 + ni * 16 + quad * 4 + r];
#pragma unroll
        for (int s = 0; s < 4; ++s) {
            U8 tmp;
            const float* wp = w1 + (size_t)ty * 8192 + (size_t)(s * 32 + quad * 8) * 64 + c;
#pragma unroll
            for (int jp = 0; jp < 4; ++jp) tmp.u[jp] = pk(wp[(2 * jp) * 64], wp[(2 * jp + 1) * 64]);
            Bf1[s][ni] = tmp.v;
        }
        // Bf2 with pi-permuted rows: element jj -> row 32*s + 16*(jj>>2) + 4*quad + (jj&3)
#pragma unroll
        for (int s = 0; s < 2; ++s) {
            U8 tmp;
#pragma unroll
            for (int w = 0; w < 4; ++w) {
                const int row = s * 32 + (w >> 1) * 16 + quad * 4 + (w & 1) * 2;
                const float* wp = w2 + (size_t)ty * 4096 + (size_t)row * 64 + c;
                tmp.u[w] = pk(wp[0], wp[64]);
            }
            Bf2[s][ni] = tmp.v;
        }
    }

    u16* msg = sMsg[wv];
    const int nT = (e1 - e0 + 63) >> 6;

    int mdc = 0;             // dstP (raw, clamped) for current tile, lane l = edge l
    int msn = 0, mdn = 0;    // meta for next tile (j+1)
    short8 a1[4][4];
    if (nT > 0) {  // prologue: tile-0 meta + gathers, tile-1 meta
        int ec = min(e0 + l, M - 1);
        int ms = srcP[ec];
        mdc = dstP[ec];
#pragma unroll
        for (int mi = 0; mi < 4; ++mi) {
            int rs = __shfl(ms, mi * 16 + l15);
            int rd = __shfl(mdc, mi * 16 + l15);
#pragma unroll
            for (int s = 0; s < 4; ++s) {
                const int row = (s < 2) ? rs : rd;
                a1[mi][s] = *(const short8*)(hbf + (size_t)row * 64 + (s & 1) * 32 + quad * 8);
            }
        }
        int ecn = min(e0 + 64 + l, M - 1);
        msn = srcP[ecn];
        mdn = dstP[ecn];
    }

    float carry = 0.f;   // partial sum of a key spanning consecutive tiles (wave-local)
    for (int j = 0; j < nT; ++j) {
        const int base = e0 + (j << 6);
        // meta prefetch for tile j+2 (clamped; harmless past end)
        const int ecf = min(base + 128 + l, M - 1);
        const int msf = srcP[ecf];
        const int mdf = dstP[ecf];

        // ---- fused layer1 (swapped) -> in-reg pack -> layer2, per mi ----
#pragma unroll
        for (int mi = 0; mi < 4; ++mi) {
            f32x4 acc[4] = {b1i[0], b1i[1], b1i[2], b1i[3]};  // bias in C-operand
#pragma unroll
            for (int s = 0; s < 4; ++s)
#pragma unroll
                for (int ni = 0; ni < 4; ++ni)
                    acc[ni] = __builtin_amdgcn_mfma_f32_16x16x32_bf16(Bf1[s][ni], a1[mi][s], acc[ni], 0, 0, 0);
            // a1[mi] consumed -> issue next tile's gathers for this mi now
            {
                int rs = __shfl(msn, mi * 16 + l15);
                int rd = __shfl(mdn, mi * 16 + l15);
#pragma unroll
                for (int s = 0; s < 4; ++s) {
                    const int row = (s < 2) ? rs : rd;
                    a1[mi][s] = *(const short8*)(hbf + (size_t)row * 64 + (s & 1) * 32 + quad * 8);
                }
            }
            // relu + in-register pack into layer-2 A-fragments (pi layout)
            U8 pa, pb;
#pragma unroll
            for (int ni = 0; ni < 2; ++ni) {
                float h0 = fmaxf(acc[ni][0], 0.f);
                float h1 = fmaxf(acc[ni][1], 0.f);
                float h2 = fmaxf(acc[ni][2], 0.f);
                float h3 = fmaxf(acc[ni][3], 0.f);
                pa.u[ni * 2] = pk_fast(h0, h1);
                pa.u[ni * 2 + 1] = pk_fast(h2, h3);
            }
#pragma unroll
            for (int ni = 0; ni < 2; ++ni) {
                float h0 = fmaxf(acc[2 + ni][0], 0.f);
                float h1 = fmaxf(acc[2 + ni][1], 0.f);
                float h2 = fmaxf(acc[2 + ni][2], 0.f);
                float h3 = fmaxf(acc[2 + ni][3], 0.f);
                pb.u[ni * 2] = pk_fast(h0, h1);
                pb.u[ni * 2 + 1] = pk_fast(h2, h3);
            }
            // layer 2: lane&15 = out col, regs = edges; bias in C
#pragma unroll
            for (int ni = 0; ni < 4; ++ni) {
                f32x4 tt = __builtin_amdgcn_mfma_f32_16x16x32_bf16(pa.v, Bf2[0][ni], b2i[ni], 0, 0, 0);
                f32x4 m2 = __builtin_amdgcn_mfma_f32_16x16x32_bf16(pb.v, Bf2[1][ni], tt, 0, 0, 0);
                const int c = ni * 16 + l15;
                const int e0v = mi * 16 + quad * 4;
                uint2 w;
                w.x = pk_fast(m2[0], m2[1]);
                w.y = pk_fast(m2[2], m2[3]);
                *(uint2*)(msg + c * 76 + e0v) = w;  // 8B-aligned
            }
        }

        // ---- run-reduction: plain bf16-row stores; carry across tiles ----
        {
            const int eg = base + l;
            const int dvz = (eg < e1) ? mdc : -1;
            const int dprev = __shfl_up(dvz, 1);
            const u64 mask = __ballot((l == 0) || (dvz != dprev));
            const int dnext = (base + 64 < e1) ? __shfl(mdn, 0) : -1;
            float a = carry;
            carry = 0.f;
#pragma unroll
            for (int i = 0; i < 64; i += 4) {
                uint2 pr = *(const uint2*)(msg + l * 76 + i);
                float v0 = bflo(pr.x), v1 = bfhi(pr.x), v2 = bflo(pr.y), v3 = bfhi(pr.y);
#define RR_STEP(ii, vv)                                                         \
                a += (vv);                                                      \
                if ((ii) == 63) {                                               \
                    int dd = __builtin_amdgcn_readlane(dvz, 63);                \
                    if (dd >= 0) {                                              \
                        if (dd == dnext) carry = a;                             \
                        else aggT[(size_t)dd * 64 + l] = (u16)f2bf(a);          \
                    }                                                           \
                } else if ((mask >> ((ii) + 1)) & 1ull) {                       \
                    int dd = __builtin_amdgcn_readlane(dvz, (ii));              \
                    if (dd >= 0) aggT[(size_t)dd * 64 + l] = (u16)f2bf(a);      \
                    a = 0.f;                                                    \
                }
                RR_STEP(i, v0)
                RR_STEP(i + 1, v1)
                RR_STEP(i + 2, v2)
                RR_STEP(i + 3, v3)
#undef RR_STEP
            }
        }
        // rotate meta pipeline
        mdc = mdn;
        msn = msf;
        mdn = mdf;
    }
}

// ---------- GRU via MFMA (bf16 type-split agg, bf16 state), fused readout ----------
// Round-19: grid 1024 -> 512. Time accounting across rounds shows ~410us outside
// edge_mlp; gru's per-block weight staging (~114KB global->LDS + barrier) vs only
// ~1.5 tiles/wave of real work makes staging ~half the kernel. 512 blocks stage
// once for ~3 tiles/wave (staging work halves). Loop is grid-stride-correct.
__global__ __launch_bounds__(256, 2) void k_gru_gemm(
    u16* __restrict__ aggB, u16* __restrict__ hbf,
    const float* __restrict__ wi, const float* __restrict__ wh,
    const float* __restrict__ bi, const float* __restrict__ bh, int n_nodes, int last,
    const float* __restrict__ ro_w1, const float* __restrict__ ro_b1,
    const float* __restrict__ ro_w2, const float* __restrict__ ro_b2,
    const float* __restrict__ x, const int* __restrict__ node_type, float* __restrict__ out) {
    extern __shared__ u16 smem[];
    u16* sRZ = smem;                 // 128 cols x stride 136 (r|z), K=128=[agg|h]
    u16* sIN = smem + 128 * 136;     // 64 cols x stride 72, K=64 (agg)
    u16* sHN = sIN + 64 * 72;        // 64 cols x stride 72, K=64 (h)
    u16* sTR = sHN + 64 * 72;        // 4 waves x (16 nodes x stride 72) output transpose
    u16* sRO = sTR + 4 * 16 * 72;    // readout W1, 64 cols x stride 72

    const int tid = threadIdx.x;
    const int l = tid & 63, wv = tid >> 6;
    const int l15 = l & 15, quad = l >> 4;
    const f32x4 vz = {0.f, 0.f, 0.f, 0.f};

    for (int u = tid; u < 128 * 64; u += 256) {
        int c = u & 127, k0 = (u >> 7) * 2;
        float v0 = (k0 < 64) ? wi[k0 * 192 + c] : wh[(k0 - 64) * 192 + c];
        float v1 = (k0 < 64) ? wi[(k0 + 1) * 192 + c] : wh[(k0 + 1 - 64) * 192 + c];
        *(u32*)(sRZ + c * 136 + k0) = pk(v0, v1);
    }
    for (int u = tid; u < 64 * 32; u += 256) {
        int c = u & 63, k0 = (u >> 6) * 2;
        *(u32*)(sIN + c * 72 + k0) = pk(wi[k0 * 192 + 128 + c], wi[(k0 + 1) * 192 + 128 + c]);
        *(u32*)(sHN + c * 72 + k0) = pk(wh[k0 * 192 + 128 + c], wh[(k0 + 1) * 192 + 128 + c]);
        *(u32*)(sRO + c * 72 + k0) = pk(ro_w1[k0 * 64 + c], ro_w1[(k0 + 1) * 64 + c]);
    }
    float bR[4], bZ[4], bI[4], bH[4], b1v[4], w2v[4];
#pragma unroll
    for (int nt = 0; nt < 4; ++nt) {
        int j = nt * 16 + l15;
        bR[nt] = bi[j] + bh[j];
        bZ[nt] = bi[64 + j] + bh[64 + j];
        bI[nt] = bi[128 + j];
        bH[nt] = bh[128 + j];
        b1v[nt] = ro_b1[j];
        w2v[nt] = ro_w2[j];
    }
    const float b2s = ro_b2[0];
    __syncthreads();  // the only barrier

    u16* tr = sTR + wv * (16 * 72);
    const int n_tiles = (n_nodes + 15) >> 4;
    const int g = blockIdx.x & 7, jb = blockIdx.x >> 3, nbg = gridDim.x >> 3;
    const int per8 = (n_tiles + 7) >> 3;
    const int glo = g * per8, ghi = min(glo + per8, n_tiles);
    for (int tile = glo + jb * 4 + wv; tile < ghi; tile += nbg * 4) {
        const int nb = tile << 4;
        const int arow = nb + l15;
        const int rowc = (arow < n_nodes) ? arow : (n_nodes - 1);
        short8 aA0[2], aA1[2], aH[2];
#pragma unroll
        for (int s = 0; s < 2; ++s) {
            aA0[s] = *(const short8*)(aggB + (size_t)rowc * 64 + s * 32 + quad * 8);
            aA1[s] = *(const short8*)(aggB + ((size_t)n_nodes + rowc) * 64 + s * 32 + quad * 8);
            aH[s]  = *(const short8*)(hbf + (size_t)rowc * 64 + s * 32 + quad * 8);
        }
        // re-zero both agg rows for the next layer (rows exclusively ours; skip on last)
        if (!last && arow < n_nodes) {
            const uint4 z16 = {0u, 0u, 0u, 0u};
#pragma unroll
            for (int s = 0; s < 2; ++s) {
                *(uint4*)(aggB + (size_t)rowc * 64 + s * 32 + quad * 8) = z16;
                *(uint4*)(aggB + ((size_t)n_nodes + rowc) * 64 + s * 32 + quad * 8) = z16;
            }
        }
        f32x4 D[16];
#pragma unroll
        for (int i = 0; i < 16; ++i) D[i] = vz;
#pragma unroll
        for (int nt = 0; nt < 8; ++nt) {
            const u16* bp = sRZ + (nt * 16 + l15) * 136 + quad * 8;
            D[nt] = __builtin_amdgcn_mfma_f32_16x16x32_bf16(aA0[0], *(const short8*)bp, D[nt], 0, 0, 0);
            D[nt] = __builtin_amdgcn_mfma_f32_16x16x32_bf16(aA0[1], *(const short8*)(bp + 32), D[nt], 0, 0, 0);
            D[nt] = __builtin_amdgcn_mfma_f32_16x16x32_bf16(aA1[0], *(const short8*)bp, D[nt], 0, 0, 0);
            D[nt] = __builtin_amdgcn_mfma_f32_16x16x32_bf16(aA1[1], *(const short8*)(bp + 32), D[nt], 0, 0, 0);
            D[nt] = __builtin_amdgcn_mfma_f32_16x16x32_bf16(aH[0], *(const short8*)(bp + 64), D[nt], 0, 0, 0);
            D[nt] = __builtin_amdgcn_mfma_f32_16x16x32_bf16(aH[1], *(const short8*)(bp + 96), D[nt], 0, 0, 0);
        }
#pragma unroll
        for (int nt = 0; nt < 4; ++nt) {
            const u16* ip = sIN + (nt * 16 + l15) * 72 + quad * 8;
            D[8 + nt] = __builtin_amdgcn_mfma_f32_16x16x32_bf16(aA0[0], *(const short8*)ip, D[8 + nt], 0, 0, 0);
            D[8 + nt] = __builtin_amdgcn_mfma_f32_16x16x32_bf16(aA0[1], *(const short8*)(ip + 32), D[8 + nt], 0, 0, 0);
            D[8 + nt] = __builtin_amdgcn_mfma_f32_16x16x32_bf16(aA1[0], *(const short8*)ip, D[8 + nt], 0, 0, 0);
            D[8 + nt] = __builtin_amdgcn_mfma_f32_16x16x32_bf16(aA1[1], *(const short8*)(ip + 32), D[8 + nt], 0, 0, 0);
            const u16* hp = sHN + (nt * 16 + l15) * 72 + quad * 8;
            D[12 + nt] = __builtin_amdgcn_mfma_f32_16x16x32_bf16(aH[0], *(const short8*)hp, D[12 + nt], 0, 0, 0);
            D[12 + nt] = __builtin_amdgcn_mfma_f32_16x16x32_bf16(aH[1], *(const short8*)(hp + 32), D[12 + nt], 0, 0, 0);
        }
#pragma unroll
        for (int nt = 0; nt < 4; ++nt) {
            const int j = nt * 16 + l15;
#pragma unroll
            for (int r = 0; r < 4; ++r) {
                const int nd = nb + quad * 4 + r;
                float rsv = D[nt][r] + bR[nt];
                float zsv = D[4 + nt][r] + bZ[nt];
                float inv = D[8 + nt][r] + bI[nt];
                float hnv = D[12 + nt][r] + bH[nt];
                float rr = 1.f / (1.f + __expf(-rsv));
                float zz = 1.f / (1.f + __expf(-zsv));
                float nn = tanhf(fmaf(rr, hnv, inv));
                float hv = (nd < n_nodes) ? bfu(hbf[(size_t)nd * 64 + j]) : 0.f;
                float nh = (1.f - zz) * nn + zz * hv;
                tr[(quad * 4 + r) * 72 + j] = (u16)f2bf(nh);
            }
        }
        {   // coalesced write-back: lane covers 32 contiguous bytes of one node
            const int nd = nb + (l >> 2);
            if (nd < n_nodes) {
                const u16* sp = tr + (l >> 2) * 72 + (l & 3) * 16;
                uint4 va = *(const uint4*)sp;
                uint4 vb = *(const uint4*)(sp + 8);
                u16* dp = hbf + (size_t)nd * 64 + (l & 3) * 16;
                *(uint4*)dp = va;
                *(uint4*)(dp + 8) = vb;
            }
        }
        if (last) {  // fused readout
            short8 ar0 = *(const short8*)(tr + l15 * 72 + quad * 8);
            short8 ar1 = *(const short8*)(tr + l15 * 72 + 32 + quad * 8);
            float p[4] = {0.f, 0.f, 0.f, 0.f};
#pragma unroll
            for (int nt = 0; nt < 4; ++nt) {
                const u16* bp = sRO + (nt * 16 + l15) * 72 + quad * 8;
                f32x4 acc = __builtin_amdgcn_mfma_f32_16x16x32_bf16(ar0, *(const short8*)bp, vz, 0, 0, 0);
                acc = __builtin_amdgcn_mfma_f32_16x16x32_bf16(ar1, *(const short8*)(bp + 32), acc, 0, 0, 0);
#pragma unroll
                for (int r = 0; r < 4; ++r)
                    p[r] += fmaxf(acc[r] + b1v[nt], 0.f) * w2v[nt];
            }
#pragma unroll
            for (int off = 1; off < 16; off <<= 1)
#pragma unroll
                for (int r = 0; r < 4; ++r) p[r] += __shfl_xor(p[r], off);
            if (l15 == 0) {
#pragma unroll
                for (int r = 0; r < 4; ++r) {
                    const int nd = nb + quad * 4 + r;
                    if (nd < n_nodes) {
                        float o = p[r] + b2s;
                        out[nd] = (node_type[nd] == 0) ? (x[nd * 4] + o) : 0.f;
                    }
                }
            }
        }
    }
}

extern "C" void kernel_launch(void* const* d_in, const int* in_sizes, int n_in, void* d_out,
                              int out_size, void* d_ws, size_t ws_size, hipStream_t stream) {
    const float* x = (const float*)d_in[0];
    const int* node_type = (const int*)d_in[1];
    const int* edge_index = (const int*)d_in[2];
    const int* edge_type = (const int*)d_in[3];
    const float* in_w = (const float*)d_in[4];
    const float* in_b = (const float*)d_in[5];
    const float* ln_g = (const float*)d_in[6];
    const float* ln_b = (const float*)d_in[7];
    const float* mlp_w1 = (const float*)d_in[8];
    const float* mlp_b1 = (const float*)d_in[9];
    const float* mlp_w2 = (const float*)d_in[10];
    const float* mlp_b2 = (const float*)d_in[11];
    const float* gru_wi = (const float*)d_in[12];
    const float* gru_wh = (const float*)d_in[13];
    const float* gru_bi = (const float*)d_in[14];
    const float* gru_bh = (const float*)d_in[15];
    const float* ro_w1 = (const float*)d_in[16];
    const float* ro_b1 = (const float*)d_in[17];
    const float* ro_w2 = (const float*)d_in[18];
    const float* ro_b2 = (const float*)d_in[19];

    const int N = in_sizes[1];  // nodes
    const int M = in_sizes[3];  // edges
    const int* src = edge_index;
    const int* dst = edge_index + M;

    // ws: aggB bf16 [2N][64] | hbf (N*128B) | off (2N*4) | part (4KB) | srcP | dstP | key | wEdg
    char* wsb = (char*)d_ws;
    u16* aggB = (u16*)wsb;
    u16* hbf = (u16*)(wsb + (size_t)N * 256);
    int* off = (int*)(wsb + (size_t)N * 384);
    int* part = (int*)(wsb + (size_t)N * 384 + (size_t)2 * N * 4);
    int* srcP = (int*)(wsb + (size_t)N * 384 + (size_t)2 * N * 4 + 4096);
    int* dstP = srcP + M;
    int* key = dstP + M;
    int* wEdg = key + M;
    int* t0slot = part + 1000;

    const int NB = 2 * N;
    const int nb = (NB + 1023) / 1024;
    const int nd8 = (N + 7) / 8;

    // build (type,dst)-sorted edge permutation (reused by all 3 layers)
    hipMemsetAsync(off, 0, (size_t)NB * sizeof(int), stream);
    k_hist<<<(M + 255) / 256, 256, 0, stream>>>(dst, edge_type, off, key, M, N);
    k_scan1<<<nb, 1024, 0, stream>>>(off, part, NB);
    k_scan2<<<1, 64, 0, stream>>>(part, nb);
    k_scan3<<<nb, 1024, 0, stream>>>(off, part, NB, N, t0slot);
    k_filldst<<<(NB + 255) / 256, 256, 0, stream>>>(off, dstP, NB, N, M);
    k_wsplit<<<(2 * 2049 + 255) / 256, 256, 0, stream>>>(off, wEdg, N, M);  // off = starts here
    k_scatter<<<2048, 256, 0, stream>>>(src, key, off, srcP, M, N, nd8);    // mutates off

    k_input_proj<<<(N + 3) / 4, 256, 0, stream>>>(x, in_w, in_b, ln_g, ln_b, hbf, aggB, N);
    const size_t gruLds =
        (size_t)(128 * 136 + 64 * 72 + 64 * 72 + 4 * 16 * 72 + 64 * 72) * sizeof(u16);  // 71680
    for (int l = 0; l < 3; ++l) {
        k_edge_mlp<<<1024, 256, 0, stream>>>(hbf, srcP, dstP,
                                             mlp_w1 + (size_t)l * 2 * 128 * 64,
                                             mlp_b1 + (size_t)l * 2 * 64,
                                             mlp_w2 + (size_t)l * 2 * 64 * 64,
                                             mlp_b2 + (size_t)l * 2 * 64,
                                             aggB, M, wEdg, N);
        k_gru_gemm<<<512, 256, gruLds, stream>>>(aggB, hbf, gru_wi + (size_t)l * 64 * 192,
                                                 gru_wh + (size_t)l * 64 * 192,
                                                 gru_bi + (size_t)l * 192, gru_bh + (size_t)l * 192,
                                                 N, (l == 2) ? 1 : 0,
                                                 ro_w1, ro_b1, ro_w2, ro_b2,
                                                 x, node_type, (float*)d_out);
    }
}